// Round 1
// baseline (2434.330 us; speedup 1.0000x reference)
//
#include <hip/hip_runtime.h>
#include <math.h>

// ---------------------------------------------------------------------------
// HyperbolicGraphConvolution (HGCN HypLinear + NodeSelect + HypAct), c=1.
// Round 1: correctness-first. Score/top-k path in f64 (sel boundary is the
// only knife-edge vs the f64 numpy reference); everything else f32.
// ---------------------------------------------------------------------------

#define MAXN_D 0.996      // (1 - 4e-3)/sqrt(c), c=1
#define MAXN_F 0.996f

__device__ __forceinline__ double wsumd(double v){
#pragma unroll
  for(int o=32;o;o>>=1) v += __shfl_xor(v,o,64);
  return v;
}
__device__ __forceinline__ float wsumf(float v){
#pragma unroll
  for(int o=32;o;o>>=1) v += __shfl_xor(v,o,64);
  return v;
}
__device__ __forceinline__ void atomAddF(float* p, float v){
  __hip_atomic_fetch_add(p, v, __ATOMIC_RELAXED, __HIP_MEMORY_SCOPE_AGENT);
}
__device__ __forceinline__ void atomAddD(double* p, double v){
  __hip_atomic_fetch_add(p, v, __ATOMIC_RELAXED, __HIP_MEMORY_SCOPE_AGENT);
}

// ---- K0: hyp_bias = proj(expmap0(bias)) in double, one wave -----------------
__global__ void k_bias(const float* __restrict__ bias, double* __restrict__ hb){
  int lane = threadIdx.x & 63;
  double b = (double)bias[lane];
  double n = fmax(sqrt(wsumd(b*b)), 1e-15);
  double e = tanh(n)*b/n;                       // expmap0, sc=1
  double en = fmax(sqrt(wsumd(e*e)), 1e-15);
  if(en > MAXN_D) e *= MAXN_D/en;               // proj
  hb[lane] = e;
}

// ---- K1: HypLinear + logmap0 per node (double), store f64 + f32 ------------
__global__ __launch_bounds__(256) void k_linear(
    const float* __restrict__ x, const float* __restrict__ W,
    const double* __restrict__ hb, float* __restrict__ xtf,
    double* __restrict__ xtd, int N){
  __shared__ double WT[64*64];                  // WT[k][j] = W[j][k]
  for(int idx=threadIdx.x; idx<4096; idx+=256)
    WT[(idx&63)*64 + (idx>>6)] = (double)W[idx];
  __syncthreads();
  int lane = threadIdx.x & 63;
  int i = blockIdx.x*4 + (threadIdx.x>>6);
  if(i>=N) return;
  size_t base = (size_t)i*64;
  double xv = (double)x[base+lane];
  double mx = 0.0;                              // mx[j] = sum_k x[k]*W[j][k]
  for(int kk=0; kk<64; ++kk){
    double xk = __shfl(xv, kk, 64);
    mx = fma(xk, WT[kk*64+lane], mx);
  }
  double xn2  = wsumd(xv*xv);
  double mxn2 = wsumd(mx*mx);
  bool zero = (mxn2 == 0.0);
  double xn  = fmax(sqrt(xn2), 1e-15);
  double mxn = fmax(sqrt(mxn2), 1e-15);
  double xc  = fmin(fmax(xn, -1.0+1e-7), 1.0-1e-7);
  double at  = 0.5*(log1p(xc)-log1p(-xc));      // artanh
  double h   = tanh(mxn/xn*at) * mx / mxn;      // mobius_matvec, sc=1
  if(zero) h = 0.0;
  double hn = fmax(sqrt(wsumd(h*h)), 1e-15);    // proj
  if(hn > MAXN_D) h *= MAXN_D/hn;
  // mobius_add(h, hyp_bias)
  double y  = hb[lane];
  double x2 = wsumd(h*h);
  double y2 = wsumd(y*y);
  double xy = wsumd(h*y);
  double num = (1.0+2.0*xy+y2)*h + (1.0-x2)*y;
  double den = fmax(1.0+2.0*xy+x2*y2, 1e-15);
  double p = num/den;
  double pn = fmax(sqrt(wsumd(p*p)), 1e-15);    // proj
  if(pn > MAXN_D) p *= MAXN_D/pn;
  // logmap0
  double n2 = fmax(sqrt(wsumd(p*p)), 1e-15);
  double nc = fmin(fmax(n2, -1.0+1e-7), 1.0-1e-7);
  double at2 = 0.5*(log1p(nc)-log1p(-nc));
  double xt = at2*p/n2;
  xtd[base+lane] = xt;
  xtf[base+lane] = (float)xt;
}

// ---- K2: edge pass A: sum_neigh[dst] += x_tan[src]; deg[src] += (s!=d) -----
__global__ void k_edgeA(const int* __restrict__ ei, const float* __restrict__ xtf,
                        float* __restrict__ sumn, int* __restrict__ deg, int E){
  int lane = threadIdx.x & 63;
  long long wid = ((long long)blockIdx.x*blockDim.x + threadIdx.x)>>6;
  long long stride = ((long long)gridDim.x*blockDim.x)>>6;
  for(long long e=wid; e<E; e+=stride){
    int s = ei[e], d = ei[(size_t)E+e];
    float v = xtf[(size_t)s*64+lane];
    atomAddF(&sumn[(size_t)d*64+lane], v);
    if(lane==0 && s!=d) atomicAdd(&deg[s], 1);
  }
}

// ---- K3: dinv = deg>0 ? deg^-0.5 : 0 (double) ------------------------------
__global__ void k_dinv(const int* __restrict__ deg, double* __restrict__ dinv, int N){
  int i = blockIdx.x*blockDim.x + threadIdx.x;
  if(i<N){ int d = deg[i]; dinv[i] = (d>0) ? 1.0/sqrt((double)d) : 0.0; }
}

// ---- K4: edge pass B (double): acc[dst] += -(dinv[s]*dinv[d]) * x_tan[src] -
__global__ void k_edgeB(const int* __restrict__ ei, const double* __restrict__ xtd,
                        const double* __restrict__ dinv, double* __restrict__ acc, int E){
  int lane = threadIdx.x & 63;
  long long wid = ((long long)blockIdx.x*blockDim.x + threadIdx.x)>>6;
  long long stride = ((long long)gridDim.x*blockDim.x)>>6;
  for(long long e=wid; e<E; e+=stride){
    int s = ei[e], d = ei[(size_t)E+e];
    if(s==d) continue;                    // w = 0
    double nw = -(dinv[s]*dinv[d]);
    if(nw == 0.0) continue;
    double v = xtd[(size_t)s*64+lane];
    atomAddD(&acc[(size_t)d*64+lane], nw*v);
  }
}

// ---- K5: score keys (double, monotone uint64 bits of positive score) -------
__global__ void k_score(const double* __restrict__ xtd, const double* __restrict__ acc,
                        unsigned long long* __restrict__ keys, int N){
  int lane = threadIdx.x & 63;
  int i = (blockIdx.x*blockDim.x + threadIdx.x)>>6;
  if(i>=N) return;
  size_t b = (size_t)i*64;
  double v = fabs(xtd[b+lane] + acc[b+lane]);
  double s = wsumd(v);
  if(lane==0) keys[i] = (unsigned long long)__double_as_longlong(s);
}

// ---- K6: radix select: keyT = k-th largest key (exact), single block -------
__global__ void k_select(const unsigned long long* __restrict__ keys, int N, int kth,
                         unsigned long long* __restrict__ keyT){
  __shared__ int h[256];
  __shared__ unsigned long long pref;
  __shared__ int rem;
  if(threadIdx.x==0){ pref=0ull; rem=kth; }
  __syncthreads();
  for(int lev=0; lev<8; ++lev){
    int shift = 56 - 8*lev;
    h[threadIdx.x] = 0;
    __syncthreads();
    int lane = threadIdx.x & 63;
    for(int base=0; base<N; base+=256){
      int i = base + (int)threadIdx.x;
      bool m = false; int dig = 0;
      if(i<N){
        unsigned long long kk = keys[i];
        m = (lev==0) || ((kk >> (shift+8)) == (pref >> (shift+8)));
        dig = (int)((kk>>shift)&255);
      }
      unsigned long long act = __ballot(m);
      if(act == ~0ull){
        int dl = __shfl(dig, 0, 64);
        if(__ballot(dig==dl) == ~0ull){ if(lane==0) atomicAdd(&h[dl],64); }
        else atomicAdd(&h[dig],1);
      } else if(m) atomicAdd(&h[dig],1);
    }
    __syncthreads();
    if(threadIdx.x==0){
      int cum=0, chosen=0;
      for(int d=255; d>=0; --d){
        cum += h[d];
        if(cum>=rem){ chosen=d; rem -= (cum - h[d]); break; }
      }
      pref |= ((unsigned long long)chosen) << shift;
    }
    __syncthreads();
  }
  if(threadIdx.x==0) *keyT = pref;
}

// ---- K7: edge pass C: sum_sel[dst] += sel[src]*x_tan[src] ------------------
__global__ void k_edgeC(const int* __restrict__ ei, const float* __restrict__ xtf,
                        const unsigned long long* __restrict__ keys,
                        const unsigned long long* __restrict__ keyT,
                        float* __restrict__ sums, int E){
  unsigned long long T = *keyT;
  int lane = threadIdx.x & 63;
  long long wid = ((long long)blockIdx.x*blockDim.x + threadIdx.x)>>6;
  long long stride = ((long long)gridDim.x*blockDim.x)>>6;
  for(long long e=wid; e<E; e+=stride){
    int s = ei[e], d = ei[(size_t)E+e];
    if(keys[s] > T){
      atomAddF(&sums[(size_t)d*64+lane], xtf[(size_t)s*64+lane]);
    }
  }
}

// ---- K8: gate = sigmoid([sum_sel, sum_neigh] @ lw_w^T + lw_b) --------------
__global__ void k_gate(const float* __restrict__ sums, const float* __restrict__ sumn,
                       const float* __restrict__ lww, const float* __restrict__ lwb,
                       float* __restrict__ gate, int N){
  int lane = threadIdx.x & 63;
  int i = (blockIdx.x*blockDim.x + threadIdx.x)>>6;
  if(i>=N) return;
  size_t b = (size_t)i*64;
  float z = sums[b+lane]*lww[lane] + sumn[b+lane]*lww[64+lane];
  z = wsumf(z);
  if(lane==0) gate[i] = 1.f/(1.f+expf(-(z+lwb[0])));
}

// ---- K9: edge pass D: ax[dst] += gate[src]*sel[src]*x_tan[src] -------------
__global__ void k_edgeD(const int* __restrict__ ei, const float* __restrict__ xtf,
                        const unsigned long long* __restrict__ keys,
                        const unsigned long long* __restrict__ keyT,
                        const float* __restrict__ gate, float* __restrict__ ax, int E){
  unsigned long long T = *keyT;
  int lane = threadIdx.x & 63;
  long long wid = ((long long)blockIdx.x*blockDim.x + threadIdx.x)>>6;
  long long stride = ((long long)gridDim.x*blockDim.x)>>6;
  for(long long e=wid; e<E; e+=stride){
    int s = ei[e], d = ei[(size_t)E+e];
    if(keys[s] > T){
      float g = gate[s];
      atomAddF(&ax[(size_t)d*64+lane], g*xtf[(size_t)s*64+lane]);
    }
  }
}

// ---- K10: out = proj(expmap0(relu(proj(expmap0(x_tan + relu(ax)))))) -------
__global__ void k_final(const float* __restrict__ xtf, const float* __restrict__ ax,
                        float* __restrict__ out, int N){
  int lane = threadIdx.x & 63;
  int i = (blockIdx.x*blockDim.x + threadIdx.x)>>6;
  if(i>=N) return;
  size_t b = (size_t)i*64;
  float a = fmaxf(ax[b+lane], 0.f);          // relu on aggregate
  float v = xtf[b+lane] + a;
  float n = fmaxf(sqrtf(wsumf(v*v)), 1e-15f);
  float e = tanhf(n)*v/n;                    // expmap0
  float en = fmaxf(sqrtf(wsumf(e*e)), 1e-15f);
  if(en > MAXN_F) e *= MAXN_F/en;            // proj
  e = fmaxf(e, 0.f);                         // relu (HypAct)
  float n2 = fmaxf(sqrtf(wsumf(e*e)), 1e-15f);
  float e2 = tanhf(n2)*e/n2;                 // expmap0
  float e2n = fmaxf(sqrtf(wsumf(e2*e2)), 1e-15f);
  if(e2n > MAXN_F) e2 *= MAXN_F/e2n;         // proj
  out[b+lane] = e2;
}

// ---------------------------------------------------------------------------
extern "C" void kernel_launch(void* const* d_in, const int* in_sizes, int n_in,
                              void* d_out, int out_size, void* d_ws, size_t ws_size,
                              hipStream_t stream){
  const float* x    = (const float*)d_in[0];
  const int*   ei   = (const int*)d_in[1];
  const float* W    = (const float*)d_in[2];
  const float* bias = (const float*)d_in[3];
  const float* lww  = (const float*)d_in[4];
  const float* lwb  = (const float*)d_in[5];
  int N = in_sizes[0]/64;
  int E = in_sizes[1]/2;
  int kth = (int)((double)N*0.75);

  char* ws = (char*)d_ws;
  size_t cur = 0;
  auto alloc = [&](size_t bytes){ size_t o = cur; cur = (cur + bytes + 255) & ~(size_t)255; return o; };
  size_t o_hb   = alloc(64*sizeof(double));
  size_t o_keyT = alloc(8);
  size_t o_zero = cur;                         // ---- zeroed region start ----
  size_t o_deg  = alloc((size_t)N*4);
  size_t o_sumn = alloc((size_t)N*64*4);
  size_t o_sums = alloc((size_t)N*64*4);
  size_t o_ax   = alloc((size_t)N*64*4);
  size_t o_acc  = alloc((size_t)N*64*8);
  size_t zlen   = cur - o_zero;                // ---- zeroed region end ------
  size_t o_dinv = alloc((size_t)N*8);
  size_t o_keys = alloc((size_t)N*8);
  size_t o_xtf  = alloc((size_t)N*64*4);
  size_t o_xtd  = alloc((size_t)N*64*8);
  size_t o_gate = alloc((size_t)N*4);
  if(ws_size < cur) return;                    // loud, clean failure if ws too small

  double*             hb   = (double*)(ws+o_hb);
  unsigned long long* keyT = (unsigned long long*)(ws+o_keyT);
  int*                deg  = (int*)(ws+o_deg);
  float*              sumn = (float*)(ws+o_sumn);
  float*              sums = (float*)(ws+o_sums);
  float*              ax   = (float*)(ws+o_ax);
  double*             acc  = (double*)(ws+o_acc);
  double*             dinv = (double*)(ws+o_dinv);
  unsigned long long* keys = (unsigned long long*)(ws+o_keys);
  float*              xtf  = (float*)(ws+o_xtf);
  double*             xtd  = (double*)(ws+o_xtd);
  float*              gate = (float*)(ws+o_gate);

  hipMemsetAsync(ws+o_zero, 0, zlen, stream);

  int nodeBlocks = (N+3)/4;
  k_bias  <<<1, 64, 0, stream>>>(bias, hb);
  k_linear<<<nodeBlocks, 256, 0, stream>>>(x, W, hb, xtf, xtd, N);
  k_edgeA <<<8192, 256, 0, stream>>>(ei, xtf, sumn, deg, E);
  k_dinv  <<<(N+255)/256, 256, 0, stream>>>(deg, dinv, N);
  k_edgeB <<<8192, 256, 0, stream>>>(ei, xtd, dinv, acc, E);
  k_score <<<nodeBlocks, 256, 0, stream>>>(xtd, acc, keys, N);
  k_select<<<1, 256, 0, stream>>>(keys, N, kth, keyT);
  k_edgeC <<<8192, 256, 0, stream>>>(ei, xtf, keys, keyT, sums, E);
  k_gate  <<<nodeBlocks, 256, 0, stream>>>(sums, sumn, lww, lwb, gate, N);
  k_edgeD <<<8192, 256, 0, stream>>>(ei, xtf, keys, keyT, gate, ax, E);
  k_final <<<nodeBlocks, 256, 0, stream>>>(xtf, ax, (float*)d_out, N);
}

// Round 2
// 1782.906 us; speedup vs baseline: 1.3654x; 1.3654x over previous
//
#include <hip/hip_runtime.h>
#include <math.h>

// ---------------------------------------------------------------------------
// HyperbolicGraphConvolution (HGCN HypLinear + NodeSelect + HypAct), c=1.
// Round 2: parallel radix-select (was: single-block k_select = 730us, 30%).
// Score/top-k path stays f64 (sel boundary knife-edge); rest f32.
// ---------------------------------------------------------------------------

#define MAXN_D 0.996      // (1 - 4e-3)/sqrt(c), c=1
#define MAXN_F 0.996f

__device__ __forceinline__ double wsumd(double v){
#pragma unroll
  for(int o=32;o;o>>=1) v += __shfl_xor(v,o,64);
  return v;
}
__device__ __forceinline__ float wsumf(float v){
#pragma unroll
  for(int o=32;o;o>>=1) v += __shfl_xor(v,o,64);
  return v;
}
__device__ __forceinline__ void atomAddF(float* p, float v){
  __hip_atomic_fetch_add(p, v, __ATOMIC_RELAXED, __HIP_MEMORY_SCOPE_AGENT);
}
__device__ __forceinline__ void atomAddD(double* p, double v){
  __hip_atomic_fetch_add(p, v, __ATOMIC_RELAXED, __HIP_MEMORY_SCOPE_AGENT);
}

// ---- K0: hyp_bias (double) + init select state + zero hist -----------------
__global__ void k_init(const float* __restrict__ bias, double* __restrict__ hb,
                       unsigned long long* __restrict__ pref, int* __restrict__ rem,
                       int kth, int* __restrict__ hist){
  if(threadIdx.x < 64){
    int lane = threadIdx.x;
    double b = (double)bias[lane];
    double n = fmax(sqrt(wsumd(b*b)), 1e-15);
    double e = tanh(n)*b/n;                       // expmap0, sc=1
    double en = fmax(sqrt(wsumd(e*e)), 1e-15);
    if(en > MAXN_D) e *= MAXN_D/en;               // proj
    hb[lane] = e;
  }
  hist[threadIdx.x] = 0;
  if(threadIdx.x == 0){ *pref = 0ull; *rem = kth; }
}

// ---- K1: HypLinear + logmap0 per node (double), store f64 + f32 ------------
__global__ __launch_bounds__(256) void k_linear(
    const float* __restrict__ x, const float* __restrict__ W,
    const double* __restrict__ hb, float* __restrict__ xtf,
    double* __restrict__ xtd, int N){
  __shared__ double WT[64*64];                  // WT[k][j] = W[j][k]
  for(int idx=threadIdx.x; idx<4096; idx+=256)
    WT[(idx&63)*64 + (idx>>6)] = (double)W[idx];
  __syncthreads();
  int lane = threadIdx.x & 63;
  int i = blockIdx.x*4 + (threadIdx.x>>6);
  if(i>=N) return;
  size_t base = (size_t)i*64;
  double xv = (double)x[base+lane];
  double mx = 0.0;                              // mx[j] = sum_k x[k]*W[j][k]
  for(int kk=0; kk<64; ++kk){
    double xk = __shfl(xv, kk, 64);
    mx = fma(xk, WT[kk*64+lane], mx);
  }
  double xn2  = wsumd(xv*xv);
  double mxn2 = wsumd(mx*mx);
  bool zero = (mxn2 == 0.0);
  double xn  = fmax(sqrt(xn2), 1e-15);
  double mxn = fmax(sqrt(mxn2), 1e-15);
  double xc  = fmin(fmax(xn, -1.0+1e-7), 1.0-1e-7);
  double at  = 0.5*(log1p(xc)-log1p(-xc));      // artanh
  double h   = tanh(mxn/xn*at) * mx / mxn;      // mobius_matvec, sc=1
  if(zero) h = 0.0;
  double hn = fmax(sqrt(wsumd(h*h)), 1e-15);    // proj
  if(hn > MAXN_D) h *= MAXN_D/hn;
  // mobius_add(h, hyp_bias)
  double y  = hb[lane];
  double x2 = wsumd(h*h);
  double y2 = wsumd(y*y);
  double xy = wsumd(h*y);
  double num = (1.0+2.0*xy+y2)*h + (1.0-x2)*y;
  double den = fmax(1.0+2.0*xy+x2*y2, 1e-15);
  double p = num/den;
  double pn = fmax(sqrt(wsumd(p*p)), 1e-15);    // proj
  if(pn > MAXN_D) p *= MAXN_D/pn;
  // logmap0
  double n2 = fmax(sqrt(wsumd(p*p)), 1e-15);
  double nc = fmin(fmax(n2, -1.0+1e-7), 1.0-1e-7);
  double at2 = 0.5*(log1p(nc)-log1p(-nc));
  double xt = at2*p/n2;
  xtd[base+lane] = xt;
  xtf[base+lane] = (float)xt;
}

// ---- K2: deg[src] += (src!=dst), one THREAD per edge -----------------------
__global__ void k_deg(const int* __restrict__ ei, int* __restrict__ deg, int E){
  int e = blockIdx.x*blockDim.x + threadIdx.x;
  if(e < E){
    int s = ei[e], d = ei[(size_t)E+e];
    if(s != d) atomicAdd(&deg[s], 1);
  }
}

// ---- K3: dinv = deg>0 ? deg^-0.5 : 0 (double) ------------------------------
__global__ void k_dinv(const int* __restrict__ deg, double* __restrict__ dinv, int N){
  int i = blockIdx.x*blockDim.x + threadIdx.x;
  if(i<N){ int d = deg[i]; dinv[i] = (d>0) ? 1.0/sqrt((double)d) : 0.0; }
}

// ---- K4: fused edge pass: sum_neigh (f32) + info acc (f64) -----------------
__global__ void k_edgeAB(const int* __restrict__ ei, const float* __restrict__ xtf,
                         const double* __restrict__ xtd, const double* __restrict__ dinv,
                         float* __restrict__ sumn, double* __restrict__ acc, int E){
  int lane = threadIdx.x & 63;
  long long wid = ((long long)blockIdx.x*blockDim.x + threadIdx.x)>>6;
  long long stride = ((long long)gridDim.x*blockDim.x)>>6;
  for(long long e=wid; e<E; e+=stride){
    int s = ei[e], d = ei[(size_t)E+e];
    atomAddF(&sumn[(size_t)d*64+lane], xtf[(size_t)s*64+lane]);
    if(s != d){
      double nw = -(dinv[s]*dinv[d]);
      if(nw != 0.0) atomAddD(&acc[(size_t)d*64+lane], nw*xtd[(size_t)s*64+lane]);
    }
  }
}

// ---- K5: score keys (double, monotone uint64 bits of positive score) -------
__global__ void k_score(const double* __restrict__ xtd, const double* __restrict__ acc,
                        unsigned long long* __restrict__ keys, int N){
  int lane = threadIdx.x & 63;
  int i = (blockIdx.x*blockDim.x + threadIdx.x)>>6;
  if(i>=N) return;
  size_t b = (size_t)i*64;
  double v = fabs(xtd[b+lane] + acc[b+lane]);
  double s = wsumd(v);
  if(lane==0) keys[i] = (unsigned long long)__double_as_longlong(s);
}

// ---- K6a: per-level radix histogram (grid-wide, shared agg) ----------------
__global__ void k_hist(const unsigned long long* __restrict__ keys, int N,
                       const unsigned long long* __restrict__ prefp, int lev,
                       int* __restrict__ hist){
  __shared__ int h[256];
  h[threadIdx.x] = 0;
  __syncthreads();
  int shift = 56 - 8*lev;
  unsigned long long pref = *prefp;
  for(int i = blockIdx.x*blockDim.x + threadIdx.x; i<N; i += gridDim.x*blockDim.x){
    unsigned long long kk = keys[i];
    if(lev==0 || (kk >> (shift+8)) == (pref >> (shift+8)))
      atomicAdd(&h[(int)((kk>>shift)&255)], 1);
  }
  __syncthreads();
  if(h[threadIdx.x]) atomicAdd(&hist[threadIdx.x], h[threadIdx.x]);
}

// ---- K6b: pick digit, update pref/rem, re-zero hist ------------------------
__global__ void k_pick(int* __restrict__ hist, unsigned long long* __restrict__ pref,
                       int* __restrict__ rem, int lev){
  __shared__ int h[256];
  h[threadIdx.x] = hist[threadIdx.x];
  __syncthreads();
  hist[threadIdx.x] = 0;                        // reset for next level
  if(threadIdx.x == 0){
    int shift = 56 - 8*lev;
    int r = *rem, cum = 0, chosen = 0;
    for(int d=255; d>=0; --d){
      cum += h[d];
      if(cum >= r){ chosen = d; r -= (cum - h[d]); break; }
    }
    *rem = r;
    *pref |= ((unsigned long long)chosen) << shift;
  }
}

// ---- K7: edge pass C: sum_sel[dst] += sel[src]*x_tan[src] ------------------
__global__ void k_edgeC(const int* __restrict__ ei, const float* __restrict__ xtf,
                        const unsigned long long* __restrict__ keys,
                        const unsigned long long* __restrict__ keyT,
                        float* __restrict__ sums, int E){
  unsigned long long T = *keyT;
  int lane = threadIdx.x & 63;
  long long wid = ((long long)blockIdx.x*blockDim.x + threadIdx.x)>>6;
  long long stride = ((long long)gridDim.x*blockDim.x)>>6;
  for(long long e=wid; e<E; e+=stride){
    int s = ei[e], d = ei[(size_t)E+e];
    if(keys[s] > T){
      atomAddF(&sums[(size_t)d*64+lane], xtf[(size_t)s*64+lane]);
    }
  }
}

// ---- K8: gate = sigmoid([sum_sel, sum_neigh] @ lw_w^T + lw_b) --------------
__global__ void k_gate(const float* __restrict__ sums, const float* __restrict__ sumn,
                       const float* __restrict__ lww, const float* __restrict__ lwb,
                       float* __restrict__ gate, int N){
  int lane = threadIdx.x & 63;
  int i = (blockIdx.x*blockDim.x + threadIdx.x)>>6;
  if(i>=N) return;
  size_t b = (size_t)i*64;
  float z = sums[b+lane]*lww[lane] + sumn[b+lane]*lww[64+lane];
  z = wsumf(z);
  if(lane==0) gate[i] = 1.f/(1.f+expf(-(z+lwb[0])));
}

// ---- K9: edge pass D: ax[dst] += gate[src]*sel[src]*x_tan[src] -------------
__global__ void k_edgeD(const int* __restrict__ ei, const float* __restrict__ xtf,
                        const unsigned long long* __restrict__ keys,
                        const unsigned long long* __restrict__ keyT,
                        const float* __restrict__ gate, float* __restrict__ ax, int E){
  unsigned long long T = *keyT;
  int lane = threadIdx.x & 63;
  long long wid = ((long long)blockIdx.x*blockDim.x + threadIdx.x)>>6;
  long long stride = ((long long)gridDim.x*blockDim.x)>>6;
  for(long long e=wid; e<E; e+=stride){
    int s = ei[e], d = ei[(size_t)E+e];
    if(keys[s] > T){
      float g = gate[s];
      atomAddF(&ax[(size_t)d*64+lane], g*xtf[(size_t)s*64+lane]);
    }
  }
}

// ---- K10: out = proj(expmap0(relu(proj(expmap0(x_tan + relu(ax)))))) -------
__global__ void k_final(const float* __restrict__ xtf, const float* __restrict__ ax,
                        float* __restrict__ out, int N){
  int lane = threadIdx.x & 63;
  int i = (blockIdx.x*blockDim.x + threadIdx.x)>>6;
  if(i>=N) return;
  size_t b = (size_t)i*64;
  float a = fmaxf(ax[b+lane], 0.f);          // relu on aggregate
  float v = xtf[b+lane] + a;
  float n = fmaxf(sqrtf(wsumf(v*v)), 1e-15f);
  float e = tanhf(n)*v/n;                    // expmap0
  float en = fmaxf(sqrtf(wsumf(e*e)), 1e-15f);
  if(en > MAXN_F) e *= MAXN_F/en;            // proj
  e = fmaxf(e, 0.f);                         // relu (HypAct)
  float n2 = fmaxf(sqrtf(wsumf(e*e)), 1e-15f);
  float e2 = tanhf(n2)*e/n2;                 // expmap0
  float e2n = fmaxf(sqrtf(wsumf(e2*e2)), 1e-15f);
  if(e2n > MAXN_F) e2 *= MAXN_F/e2n;         // proj
  out[b+lane] = e2;
}

// ---------------------------------------------------------------------------
extern "C" void kernel_launch(void* const* d_in, const int* in_sizes, int n_in,
                              void* d_out, int out_size, void* d_ws, size_t ws_size,
                              hipStream_t stream){
  const float* x    = (const float*)d_in[0];
  const int*   ei   = (const int*)d_in[1];
  const float* W    = (const float*)d_in[2];
  const float* bias = (const float*)d_in[3];
  const float* lww  = (const float*)d_in[4];
  const float* lwb  = (const float*)d_in[5];
  int N = in_sizes[0]/64;
  int E = in_sizes[1]/2;
  int kth = (int)((double)N*0.75);

  char* ws = (char*)d_ws;
  size_t cur = 0;
  auto alloc = [&](size_t bytes){ size_t o = cur; cur = (cur + bytes + 255) & ~(size_t)255; return o; };
  size_t o_hb   = alloc(64*sizeof(double));
  size_t o_keyT = alloc(8);
  size_t o_rem  = alloc(4);
  size_t o_hist = alloc(256*4);
  size_t o_zero = cur;                         // ---- zeroed region start ----
  size_t o_deg  = alloc((size_t)N*4);
  size_t o_sumn = alloc((size_t)N*64*4);
  size_t o_sums = alloc((size_t)N*64*4);
  size_t o_ax   = alloc((size_t)N*64*4);
  size_t o_acc  = alloc((size_t)N*64*8);
  size_t zlen   = cur - o_zero;                // ---- zeroed region end ------
  size_t o_dinv = alloc((size_t)N*8);
  size_t o_keys = alloc((size_t)N*8);
  size_t o_xtf  = alloc((size_t)N*64*4);
  size_t o_xtd  = alloc((size_t)N*64*8);
  size_t o_gate = alloc((size_t)N*4);
  if(ws_size < cur) return;                    // loud, clean failure if ws too small

  double*             hb   = (double*)(ws+o_hb);
  unsigned long long* keyT = (unsigned long long*)(ws+o_keyT);
  int*                rem  = (int*)(ws+o_rem);
  int*                hist = (int*)(ws+o_hist);
  int*                deg  = (int*)(ws+o_deg);
  float*              sumn = (float*)(ws+o_sumn);
  float*              sums = (float*)(ws+o_sums);
  float*              ax   = (float*)(ws+o_ax);
  double*             acc  = (double*)(ws+o_acc);
  double*             dinv = (double*)(ws+o_dinv);
  unsigned long long* keys = (unsigned long long*)(ws+o_keys);
  float*              xtf  = (float*)(ws+o_xtf);
  double*             xtd  = (double*)(ws+o_xtd);
  float*              gate = (float*)(ws+o_gate);

  hipMemsetAsync(ws+o_zero, 0, zlen, stream);

  int nodeBlocks = (N+3)/4;
  k_init  <<<1, 256, 0, stream>>>(bias, hb, keyT, rem, kth, hist);
  k_linear<<<nodeBlocks, 256, 0, stream>>>(x, W, hb, xtf, xtd, N);
  k_deg   <<<(E+255)/256, 256, 0, stream>>>(ei, deg, E);
  k_dinv  <<<(N+255)/256, 256, 0, stream>>>(deg, dinv, N);
  k_edgeAB<<<8192, 256, 0, stream>>>(ei, xtf, xtd, dinv, sumn, acc, E);
  k_score <<<nodeBlocks, 256, 0, stream>>>(xtd, acc, keys, N);
  for(int lev=0; lev<8; ++lev){
    k_hist<<<256, 256, 0, stream>>>(keys, N, keyT, lev, hist);
    k_pick<<<1, 256, 0, stream>>>(hist, keyT, rem, lev);
  }
  k_edgeC <<<8192, 256, 0, stream>>>(ei, xtf, keys, keyT, sums, E);
  k_gate  <<<nodeBlocks, 256, 0, stream>>>(sums, sumn, lww, lwb, gate, N);
  k_edgeD <<<8192, 256, 0, stream>>>(ei, xtf, keys, keyT, gate, ax, E);
  k_final <<<nodeBlocks, 256, 0, stream>>>(xtf, ax, (float*)d_out, N);
}

// Round 3
// 1246.698 us; speedup vs baseline: 1.9526x; 1.4301x over previous
//
#include <hip/hip_runtime.h>
#include <math.h>

// ---------------------------------------------------------------------------
// HyperbolicGraphConvolution (HGCN HypLinear + NodeSelect + HypAct), c=1.
// Round 3: CSR gather restructure. Round-2 profile: k_edgeAB 677us with
// 1.44 GB HBM/dispatch from f64 atomic RMW thrash. Replace all scatter-atomic
// edge passes with dst-CSR + one-wave-per-node register gathers; fuse
// score/gate/final into the gather kernels. Score path stays f64.
// ---------------------------------------------------------------------------

#define MAXN_D 0.996      // (1 - 4e-3)/sqrt(c), c=1
#define MAXN_F 0.996f

__device__ __forceinline__ double wsumd(double v){
#pragma unroll
  for(int o=32;o;o>>=1) v += __shfl_xor(v,o,64);
  return v;
}
__device__ __forceinline__ float wsumf(float v){
#pragma unroll
  for(int o=32;o;o>>=1) v += __shfl_xor(v,o,64);
  return v;
}

// ---- K0: hyp_bias (double) + init select state + zero hist -----------------
__global__ void k_init(const float* __restrict__ bias, double* __restrict__ hb,
                       unsigned long long* __restrict__ pref, int* __restrict__ rem,
                       int kth, int* __restrict__ hist){
  if(threadIdx.x < 64){
    int lane = threadIdx.x;
    double b = (double)bias[lane];
    double n = fmax(sqrt(wsumd(b*b)), 1e-15);
    double e = tanh(n)*b/n;                       // expmap0, sc=1
    double en = fmax(sqrt(wsumd(e*e)), 1e-15);
    if(en > MAXN_D) e *= MAXN_D/en;               // proj
    hb[lane] = e;
  }
  hist[threadIdx.x] = 0;
  if(threadIdx.x == 0){ *pref = 0ull; *rem = kth; }
}

// ---- K1: HypLinear + logmap0 per node (double), store f64 + f32 ------------
__global__ __launch_bounds__(256) void k_linear(
    const float* __restrict__ x, const float* __restrict__ W,
    const double* __restrict__ hb, float* __restrict__ xtf,
    double* __restrict__ xtd, int N){
  __shared__ double WT[64*64];                  // WT[k][j] = W[j][k]
  for(int idx=threadIdx.x; idx<4096; idx+=256)
    WT[(idx&63)*64 + (idx>>6)] = (double)W[idx];
  __syncthreads();
  int lane = threadIdx.x & 63;
  int i = blockIdx.x*4 + (threadIdx.x>>6);
  if(i>=N) return;
  size_t base = (size_t)i*64;
  double xv = (double)x[base+lane];
  double mx = 0.0;                              // mx[j] = sum_k x[k]*W[j][k]
  for(int kk=0; kk<64; ++kk){
    double xk = __shfl(xv, kk, 64);
    mx = fma(xk, WT[kk*64+lane], mx);
  }
  double xn2  = wsumd(xv*xv);
  double mxn2 = wsumd(mx*mx);
  bool zero = (mxn2 == 0.0);
  double xn  = fmax(sqrt(xn2), 1e-15);
  double mxn = fmax(sqrt(mxn2), 1e-15);
  double xc  = fmin(fmax(xn, -1.0+1e-7), 1.0-1e-7);
  double at  = 0.5*(log1p(xc)-log1p(-xc));      // artanh
  double h   = tanh(mxn/xn*at) * mx / mxn;      // mobius_matvec, sc=1
  if(zero) h = 0.0;
  double hn = fmax(sqrt(wsumd(h*h)), 1e-15);    // proj
  if(hn > MAXN_D) h *= MAXN_D/hn;
  // mobius_add(h, hyp_bias)
  double y  = hb[lane];
  double x2 = wsumd(h*h);
  double y2 = wsumd(y*y);
  double xy = wsumd(h*y);
  double num = (1.0+2.0*xy+y2)*h + (1.0-x2)*y;
  double den = fmax(1.0+2.0*xy+x2*y2, 1e-15);
  double p = num/den;
  double pn = fmax(sqrt(wsumd(p*p)), 1e-15);    // proj
  if(pn > MAXN_D) p *= MAXN_D/pn;
  // logmap0
  double n2 = fmax(sqrt(wsumd(p*p)), 1e-15);
  double nc = fmin(fmax(n2, -1.0+1e-7), 1.0-1e-7);
  double at2 = 0.5*(log1p(nc)-log1p(-nc));
  double xt = at2*p/n2;
  xtd[base+lane] = xt;
  xtf[base+lane] = (float)xt;
}

// ---- K2: degrees: in-degree by dst (CSR) + out-degree (s!=d) by src --------
__global__ void k_count(const int* __restrict__ ei, int* __restrict__ degin,
                        int* __restrict__ degout, int E){
  int e = blockIdx.x*blockDim.x + threadIdx.x;
  if(e < E){
    int s = ei[e], d = ei[(size_t)E+e];
    atomicAdd(&degin[d], 1);
    if(s != d) atomicAdd(&degout[s], 1);
  }
}

// ---- K3: dinv = degout>0 ? degout^-0.5 : 0 (double) ------------------------
__global__ void k_dinv(const int* __restrict__ degout, double* __restrict__ dinv, int N){
  int i = blockIdx.x*blockDim.x + threadIdx.x;
  if(i<N){ int d = degout[i]; dinv[i] = (d>0) ? 1.0/sqrt((double)d) : 0.0; }
}

// ---- K4a/b/c: exclusive scan of degin -> rowptr (+ cursor copy) ------------
__global__ void k_scanA(const int* __restrict__ degin, int* __restrict__ excl,
                        int* __restrict__ bsum, int N){
  __shared__ int sh[256];
  int i = blockIdx.x*256 + (int)threadIdx.x;
  int v = (i<N) ? degin[i] : 0;
  sh[threadIdx.x] = v;
  __syncthreads();
  for(int off=1; off<256; off<<=1){
    int t = (threadIdx.x >= (unsigned)off) ? sh[threadIdx.x-off] : 0;
    __syncthreads();
    sh[threadIdx.x] += t;
    __syncthreads();
  }
  if(i<N) excl[i] = sh[threadIdx.x] - v;
  if(threadIdx.x == 255) bsum[blockIdx.x] = sh[255];
}
__global__ void k_scanB(int* __restrict__ bsum, int nb){
  if(threadIdx.x==0){
    int run = 0;
    for(int b=0; b<nb; ++b){ int t = bsum[b]; bsum[b] = run; run += t; }
  }
}
__global__ void k_scanC(const int* __restrict__ excl, const int* __restrict__ bsum,
                        int* __restrict__ rowptr, int* __restrict__ cursor, int N, int E){
  int i = blockIdx.x*256 + (int)threadIdx.x;
  if(i<N){
    int r = excl[i] + bsum[blockIdx.x];
    rowptr[i] = r; cursor[i] = r;
  }
  if(i==0) rowptr[N] = E;
}

// ---- K5: scatter edges into CSR (src list grouped by dst) ------------------
__global__ void k_scatter(const int* __restrict__ ei, int* __restrict__ cursor,
                          int* __restrict__ csr, int E){
  int e = blockIdx.x*blockDim.x + threadIdx.x;
  if(e < E){
    int s = ei[e], d = ei[(size_t)E+e];
    int pos = atomicAdd(&cursor[d], 1);
    csr[pos] = s;
  }
}

// ---- K6: gather pass A: sum_neigh (f32) + info score key (f64), per node ---
__global__ void k_gatherA(const int* __restrict__ csr, const int* __restrict__ rowptr,
                          const double* __restrict__ xtd, const double* __restrict__ dinv,
                          float* __restrict__ sumn, unsigned long long* __restrict__ keys,
                          int N){
  int lane = threadIdx.x & 63;
  int i = (blockIdx.x*blockDim.x + threadIdx.x)>>6;
  if(i>=N) return;
  int beg = rowptr[i], end = rowptr[i+1];
  double di = dinv[i];
  float  sn = 0.f;
  double ag = 0.0;
  for(int e=beg; e<end; ++e){
    int s = csr[e];
    double xv = xtd[(size_t)s*64+lane];
    sn += (float)xv;                      // == xtf[s], same rounding
    if(s != i) ag -= di*dinv[s]*xv;       // norm_w * x_tan[src]
  }
  size_t b = (size_t)i*64;
  sumn[b+lane] = sn;
  double v = fabs(xtd[b+lane] + ag);      // info = x_tan + agg
  double sc = wsumd(v);
  if(lane==0) keys[i] = (unsigned long long)__double_as_longlong(sc);
}

// ---- K7a: per-level radix histogram (grid-wide, shared agg) ----------------
__global__ void k_hist(const unsigned long long* __restrict__ keys, int N,
                       const unsigned long long* __restrict__ prefp, int lev,
                       int* __restrict__ hist){
  __shared__ int h[256];
  h[threadIdx.x] = 0;
  __syncthreads();
  int shift = 56 - 8*lev;
  unsigned long long pref = *prefp;
  for(int i = blockIdx.x*blockDim.x + threadIdx.x; i<N; i += gridDim.x*blockDim.x){
    unsigned long long kk = keys[i];
    if(lev==0 || (kk >> (shift+8)) == (pref >> (shift+8)))
      atomicAdd(&h[(int)((kk>>shift)&255)], 1);
  }
  __syncthreads();
  if(h[threadIdx.x]) atomicAdd(&hist[threadIdx.x], h[threadIdx.x]);
}

// ---- K7b: pick digit, update pref/rem, re-zero hist ------------------------
__global__ void k_pick(int* __restrict__ hist, unsigned long long* __restrict__ pref,
                       int* __restrict__ rem, int lev){
  __shared__ int h[256];
  h[threadIdx.x] = hist[threadIdx.x];
  __syncthreads();
  hist[threadIdx.x] = 0;                        // reset for next level
  if(threadIdx.x == 0){
    int shift = 56 - 8*lev;
    int r = *rem, cum = 0, chosen = 0;
    for(int d=255; d>=0; --d){
      cum += h[d];
      if(cum >= r){ chosen = d; r -= (cum - h[d]); break; }
    }
    *rem = r;
    *pref |= ((unsigned long long)chosen) << shift;
  }
}

// ---- K8: gather pass C + gate: sum_sel -> gate = sigmoid(...) --------------
__global__ void k_gatherC(const int* __restrict__ csr, const int* __restrict__ rowptr,
                          const float* __restrict__ xtf,
                          const unsigned long long* __restrict__ keys,
                          const unsigned long long* __restrict__ keyT,
                          const float* __restrict__ sumn,
                          const float* __restrict__ lww, const float* __restrict__ lwb,
                          float* __restrict__ gate, int N){
  unsigned long long T = *keyT;
  int lane = threadIdx.x & 63;
  int i = (blockIdx.x*blockDim.x + threadIdx.x)>>6;
  if(i>=N) return;
  int beg = rowptr[i], end = rowptr[i+1];
  float ss = 0.f;
  for(int e=beg; e<end; ++e){
    int s = csr[e];
    if(keys[s] > T) ss += xtf[(size_t)s*64+lane];
  }
  size_t b = (size_t)i*64;
  float z = ss*lww[lane] + sumn[b+lane]*lww[64+lane];
  z = wsumf(z);
  if(lane==0) gate[i] = 1.f/(1.f+expf(-(z+lwb[0])));
}

// ---- K9: gather pass D + final: ax -> out = proj(exp(relu(proj(exp(...)))))-
__global__ void k_gatherD(const int* __restrict__ csr, const int* __restrict__ rowptr,
                          const float* __restrict__ xtf,
                          const unsigned long long* __restrict__ keys,
                          const unsigned long long* __restrict__ keyT,
                          const float* __restrict__ gate,
                          float* __restrict__ out, int N){
  unsigned long long T = *keyT;
  int lane = threadIdx.x & 63;
  int i = (blockIdx.x*blockDim.x + threadIdx.x)>>6;
  if(i>=N) return;
  int beg = rowptr[i], end = rowptr[i+1];
  float ax = 0.f;
  for(int e=beg; e<end; ++e){
    int s = csr[e];
    if(keys[s] > T) ax += gate[s]*xtf[(size_t)s*64+lane];
  }
  size_t b = (size_t)i*64;
  float a = fmaxf(ax, 0.f);                  // relu on aggregate
  float v = xtf[b+lane] + a;
  float n = fmaxf(sqrtf(wsumf(v*v)), 1e-15f);
  float e1 = tanhf(n)*v/n;                   // expmap0
  float en = fmaxf(sqrtf(wsumf(e1*e1)), 1e-15f);
  if(en > MAXN_F) e1 *= MAXN_F/en;           // proj
  e1 = fmaxf(e1, 0.f);                       // relu (HypAct)
  float n2 = fmaxf(sqrtf(wsumf(e1*e1)), 1e-15f);
  float e2 = tanhf(n2)*e1/n2;                // expmap0
  float e2n = fmaxf(sqrtf(wsumf(e2*e2)), 1e-15f);
  if(e2n > MAXN_F) e2 *= MAXN_F/e2n;         // proj
  out[b+lane] = e2;
}

// ---------------------------------------------------------------------------
extern "C" void kernel_launch(void* const* d_in, const int* in_sizes, int n_in,
                              void* d_out, int out_size, void* d_ws, size_t ws_size,
                              hipStream_t stream){
  const float* x    = (const float*)d_in[0];
  const int*   ei   = (const int*)d_in[1];
  const float* W    = (const float*)d_in[2];
  const float* bias = (const float*)d_in[3];
  const float* lww  = (const float*)d_in[4];
  const float* lwb  = (const float*)d_in[5];
  int N = in_sizes[0]/64;
  int E = in_sizes[1]/2;
  int kth = (int)((double)N*0.75);
  int nb = (N+255)/256;                        // scan blocks

  char* ws = (char*)d_ws;
  size_t cur = 0;
  auto alloc = [&](size_t bytes){ size_t o = cur; cur = (cur + bytes + 255) & ~(size_t)255; return o; };
  size_t o_hb   = alloc(64*sizeof(double));
  size_t o_keyT = alloc(8);
  size_t o_rem  = alloc(4);
  size_t o_hist = alloc(256*4);
  size_t o_zero = cur;                         // ---- zeroed region start ----
  size_t o_din  = alloc((size_t)N*4);          // in-degree (CSR)
  size_t o_dout = alloc((size_t)N*4);          // out-degree (s!=d)
  size_t zlen   = cur - o_zero;                // ---- zeroed region end ------
  size_t o_excl = alloc((size_t)N*4);
  size_t o_bsum = alloc((size_t)(nb+1)*4);
  size_t o_rowp = alloc((size_t)(N+1)*4);
  size_t o_curs = alloc((size_t)N*4);
  size_t o_csr  = alloc((size_t)E*4);
  size_t o_dinv = alloc((size_t)N*8);
  size_t o_keys = alloc((size_t)N*8);
  size_t o_sumn = alloc((size_t)N*64*4);
  size_t o_xtf  = alloc((size_t)N*64*4);
  size_t o_xtd  = alloc((size_t)N*64*8);
  size_t o_gate = alloc((size_t)N*4);
  if(ws_size < cur) return;                    // loud, clean failure if ws too small

  double*             hb     = (double*)(ws+o_hb);
  unsigned long long* keyT   = (unsigned long long*)(ws+o_keyT);
  int*                rem    = (int*)(ws+o_rem);
  int*                hist   = (int*)(ws+o_hist);
  int*                degin  = (int*)(ws+o_din);
  int*                degout = (int*)(ws+o_dout);
  int*                excl   = (int*)(ws+o_excl);
  int*                bsum   = (int*)(ws+o_bsum);
  int*                rowptr = (int*)(ws+o_rowp);
  int*                cursor = (int*)(ws+o_curs);
  int*                csr    = (int*)(ws+o_csr);
  double*             dinv   = (double*)(ws+o_dinv);
  unsigned long long* keys   = (unsigned long long*)(ws+o_keys);
  float*              sumn   = (float*)(ws+o_sumn);
  float*              xtf    = (float*)(ws+o_xtf);
  double*             xtd    = (double*)(ws+o_xtd);
  float*              gate   = (float*)(ws+o_gate);

  hipMemsetAsync(ws+o_zero, 0, zlen, stream);

  int nodeBlocks = (N+3)/4;                    // 1 wave per node, 4 waves/block
  k_init   <<<1, 256, 0, stream>>>(bias, hb, keyT, rem, kth, hist);
  k_linear <<<nodeBlocks, 256, 0, stream>>>(x, W, hb, xtf, xtd, N);
  k_count  <<<(E+255)/256, 256, 0, stream>>>(ei, degin, degout, E);
  k_dinv   <<<(N+255)/256, 256, 0, stream>>>(degout, dinv, N);
  k_scanA  <<<nb, 256, 0, stream>>>(degin, excl, bsum, N);
  k_scanB  <<<1, 64, 0, stream>>>(bsum, nb);
  k_scanC  <<<nb, 256, 0, stream>>>(excl, bsum, rowptr, cursor, N, E);
  k_scatter<<<(E+255)/256, 256, 0, stream>>>(ei, cursor, csr, E);
  k_gatherA<<<nodeBlocks, 256, 0, stream>>>(csr, rowptr, xtd, dinv, sumn, keys, N);
  for(int lev=0; lev<8; ++lev){
    k_hist<<<256, 256, 0, stream>>>(keys, N, keyT, lev, hist);
    k_pick<<<1, 256, 0, stream>>>(hist, keyT, rem, lev);
  }
  k_gatherC<<<nodeBlocks, 256, 0, stream>>>(csr, rowptr, xtf, keys, keyT, sumn, lww, lwb, gate, N);
  k_gatherD<<<nodeBlocks, 256, 0, stream>>>(csr, rowptr, xtf, keys, keyT, gate, (float*)d_out, N);
}

// Round 4
// 913.575 us; speedup vs baseline: 2.6646x; 1.3646x over previous
//
#include <hip/hip_runtime.h>
#include <math.h>

// ---------------------------------------------------------------------------
// HyperbolicGraphConvolution (HGCN HypLinear + NodeSelect + HypAct), c=1.
// Round 4: linear-path refactor. Round-3 profile: k_linear 482us, wave-
// redundant f64 transcendental chain + 128 ds_bpermute/node. Algebra:
// x_tan = alpha*mx + beta*hb with per-node scalars from 3 reductions.
// -> tiled f64 GEMM (no shuffles) + lane-per-node scalar chain + streaming
// apply. Score/top-k stays f64 (sel boundary knife-edge); rest f32.
// ---------------------------------------------------------------------------

#define MAXN_D 0.996      // (1 - 4e-3)/sqrt(c), c=1
#define MAXN_F 0.996f
#define NPB 16            // nodes per block in k_gemm

__device__ __forceinline__ double wsumd(double v){
#pragma unroll
  for(int o=32;o;o>>=1) v += __shfl_xor(v,o,64);
  return v;
}
__device__ __forceinline__ float wsumf(float v){
#pragma unroll
  for(int o=32;o;o>>=1) v += __shfl_xor(v,o,64);
  return v;
}

// ---- K0: hyp_bias (double) + |hb|^2 + init select state --------------------
__global__ void k_init(const float* __restrict__ bias, double* __restrict__ hb,
                       double* __restrict__ hb2, unsigned long long* __restrict__ pref,
                       int* __restrict__ rem, int kth, int* __restrict__ hist){
  if(threadIdx.x < 64){
    int lane = threadIdx.x;
    double b = (double)bias[lane];
    double n = fmax(sqrt(wsumd(b*b)), 1e-15);
    double e = tanh(n)*b/n;                       // expmap0, sc=1
    double en = fmax(sqrt(wsumd(e*e)), 1e-15);
    if(en > MAXN_D) e *= MAXN_D/en;               // proj
    hb[lane] = e;
    double s2 = wsumd(e*e);
    if(lane==0) *hb2 = s2;
  }
  hist[threadIdx.x] = 0;
  if(threadIdx.x == 0){ *pref = 0ull; *rem = kth; }
}

// ---- K1: mx = x @ W^T (f64, LDS-tiled) + per-node reductions ---------------
// r1=|x|^2, r2=|mx|^2, r3=<mx,hb>. Wave holds full mx row (lane=j).
__global__ __launch_bounds__(256) void k_gemm(
    const float* __restrict__ x, const float* __restrict__ W,
    const double* __restrict__ hb, double* __restrict__ mx,
    double* __restrict__ r1, double* __restrict__ r2, double* __restrict__ r3,
    int N){
  __shared__ double wlds[4096];     // double2 [k2][j]: flat (k>>1)*128 + j*2 + (k&1)
  __shared__ double xlds[NPB*64];   // [n][k] f64
  int tid = threadIdx.x;
  for(int idx=tid; idx<4096; idx+=256){
    int j = idx>>6, k = idx&63;
    wlds[(k>>1)*128 + j*2 + (k&1)] = (double)W[idx];
  }
  int i0 = blockIdx.x*NPB;
  for(int idx=tid; idx<NPB*64; idx+=256){
    int node = i0 + (idx>>6);
    xlds[idx] = (node<N) ? (double)x[(size_t)node*64 + (idx&63)] : 0.0;
  }
  __syncthreads();
  int lane = tid & 63;
  int nb = (tid>>6)*4;              // this wave's first node-in-block
  double hbl = hb[lane];
  double acc0=0.0, acc1=0.0, acc2=0.0, acc3=0.0;
  const double2* w2 = (const double2*)wlds;
  const double2* x2 = (const double2*)xlds;
#pragma unroll 4
  for(int k2=0; k2<32; ++k2){
    double2 wt = w2[k2*64 + lane];          // contiguous b128 across lanes
    double2 a  = x2[(nb+0)*32 + k2];        // wave-uniform broadcasts
    double2 b  = x2[(nb+1)*32 + k2];
    double2 c  = x2[(nb+2)*32 + k2];
    double2 d  = x2[(nb+3)*32 + k2];
    acc0 = fma(wt.x, a.x, acc0); acc0 = fma(wt.y, a.y, acc0);
    acc1 = fma(wt.x, b.x, acc1); acc1 = fma(wt.y, b.y, acc1);
    acc2 = fma(wt.x, c.x, acc2); acc2 = fma(wt.y, c.y, acc2);
    acc3 = fma(wt.x, d.x, acc3); acc3 = fma(wt.y, d.y, acc3);
  }
#define DO_NODE(n, accn) { int node = i0 + nb + (n); if(node<N){            \
    double xd = xlds[(nb+(n))*64 + lane];                                   \
    mx[(size_t)node*64 + lane] = accn;                                      \
    double s1 = wsumd(xd*xd);                                               \
    double s2 = wsumd(accn*accn);                                           \
    double s3 = wsumd(accn*hbl);                                            \
    if(lane==0){ r1[node]=s1; r2[node]=s2; r3[node]=s3; } } }
  DO_NODE(0,acc0) DO_NODE(1,acc1) DO_NODE(2,acc2) DO_NODE(3,acc3)
#undef DO_NODE
}

// ---- K2: per-node scalar chain (one LANE per node) -> alpha, beta ----------
__global__ void k_chain(const double* __restrict__ r1, const double* __restrict__ r2,
                        const double* __restrict__ r3, const double* __restrict__ hb2p,
                        double* __restrict__ alpha, double* __restrict__ beta, int N){
  int i = blockIdx.x*blockDim.x + threadIdx.x;
  if(i>=N) return;
  double x2s = r1[i], m2 = r2[i], mh = r3[i];
  double y2 = *hb2p;
  double xn  = fmax(sqrt(x2s), 1e-15);
  double mxn = fmax(sqrt(m2), 1e-15);
  double xc  = fmin(fmax(xn, -1.0+1e-7), 1.0-1e-7);
  double at  = 0.5*(log1p(xc)-log1p(-xc));        // artanh(|x|)
  double f1  = tanh(mxn/xn*at)/mxn;               // h = f1*mx, f1 >= 0
  if(m2 == 0.0) f1 = 0.0;                         // zero-mask (all mx==0)
  double h2 = f1*f1*m2;
  double hn = fmax(sqrt(h2), 1e-15);
  if(hn > MAXN_D){ double s = MAXN_D/hn; f1 *= s; h2 = f1*f1*m2; }   // proj(h)
  // mobius_add(h, hb): p = a*h + b*hb
  double xy = f1*mh;                              // <h, hb>
  double den = fmax(1.0 + 2.0*xy + h2*y2, 1e-15);
  double a = (1.0 + 2.0*xy + y2)/den;
  double b = (1.0 - h2)/den;
  double p2 = a*a*h2 + 2.0*a*b*xy + b*b*y2;       // |p|^2
  double pn = fmax(sqrt(p2), 1e-15);
  if(pn > MAXN_D){ double s = MAXN_D/pn; a*=s; b*=s; pn = fmax(pn*s, 1e-15); } // proj(p)
  double nc  = fmin(fmax(pn, -1.0+1e-7), 1.0-1e-7);
  double at2 = 0.5*(log1p(nc)-log1p(-nc));        // artanh(|p|)
  double sc  = at2/pn;                            // logmap0 scale
  alpha[i] = sc*a*f1;
  beta[i]  = sc*b;
}

// ---- K3: x_tan = alpha*mx + beta*hb (streaming), write f64 + f32 -----------
__global__ void k_apply(const double* __restrict__ mx, const double* __restrict__ alpha,
                        const double* __restrict__ beta, const double* __restrict__ hb,
                        double* __restrict__ xtd, float* __restrict__ xtf, int N){
  size_t idx = (size_t)blockIdx.x*blockDim.x + threadIdx.x;
  if(idx >= (size_t)N*64) return;
  int i = (int)(idx>>6);
  double v = alpha[i]*mx[idx] + beta[i]*hb[idx&63];
  xtd[idx] = v;
  xtf[idx] = (float)v;
}

// ---- K4: degrees: in-degree by dst (CSR) + out-degree (s!=d) by src --------
__global__ void k_count(const int* __restrict__ ei, int* __restrict__ degin,
                        int* __restrict__ degout, int E){
  int e = blockIdx.x*blockDim.x + threadIdx.x;
  if(e < E){
    int s = ei[e], d = ei[(size_t)E+e];
    atomicAdd(&degin[d], 1);
    if(s != d) atomicAdd(&degout[s], 1);
  }
}

// ---- K5: dinv = degout>0 ? degout^-0.5 : 0 (double) ------------------------
__global__ void k_dinv(const int* __restrict__ degout, double* __restrict__ dinv, int N){
  int i = blockIdx.x*blockDim.x + threadIdx.x;
  if(i<N){ int d = degout[i]; dinv[i] = (d>0) ? 1.0/sqrt((double)d) : 0.0; }
}

// ---- K6a/b/c: exclusive scan of degin -> rowptr (+ cursor copy) ------------
__global__ void k_scanA(const int* __restrict__ degin, int* __restrict__ excl,
                        int* __restrict__ bsum, int N){
  __shared__ int sh[256];
  int i = blockIdx.x*256 + (int)threadIdx.x;
  int v = (i<N) ? degin[i] : 0;
  sh[threadIdx.x] = v;
  __syncthreads();
  for(int off=1; off<256; off<<=1){
    int t = (threadIdx.x >= (unsigned)off) ? sh[threadIdx.x-off] : 0;
    __syncthreads();
    sh[threadIdx.x] += t;
    __syncthreads();
  }
  if(i<N) excl[i] = sh[threadIdx.x] - v;
  if(threadIdx.x == 255) bsum[blockIdx.x] = sh[255];
}
__global__ void k_scanB(int* __restrict__ bsum, int nb){
  if(threadIdx.x==0){
    int run = 0;
    for(int b=0; b<nb; ++b){ int t = bsum[b]; bsum[b] = run; run += t; }
  }
}
__global__ void k_scanC(const int* __restrict__ excl, const int* __restrict__ bsum,
                        int* __restrict__ rowptr, int* __restrict__ cursor, int N, int E){
  int i = blockIdx.x*256 + (int)threadIdx.x;
  if(i<N){
    int r = excl[i] + bsum[blockIdx.x];
    rowptr[i] = r; cursor[i] = r;
  }
  if(i==0) rowptr[N] = E;
}

// ---- K7: scatter edges into CSR (src list grouped by dst) ------------------
__global__ void k_scatter(const int* __restrict__ ei, int* __restrict__ cursor,
                          int* __restrict__ csr, int E){
  int e = blockIdx.x*blockDim.x + threadIdx.x;
  if(e < E){
    int s = ei[e], d = ei[(size_t)E+e];
    int pos = atomicAdd(&cursor[d], 1);
    csr[pos] = s;
  }
}

// ---- K8: gather pass A: sum_neigh (f32) + info score key (f64), per node ---
__global__ void k_gatherA(const int* __restrict__ csr, const int* __restrict__ rowptr,
                          const double* __restrict__ xtd, const double* __restrict__ dinv,
                          float* __restrict__ sumn, unsigned long long* __restrict__ keys,
                          int N){
  int lane = threadIdx.x & 63;
  int i = (blockIdx.x*blockDim.x + threadIdx.x)>>6;
  if(i>=N) return;
  int beg = rowptr[i], end = rowptr[i+1];
  double di = dinv[i];
  float  sn = 0.f;
  double ag = 0.0;
  for(int e=beg; e<end; ++e){
    int s = csr[e];
    double xv = xtd[(size_t)s*64+lane];
    sn += (float)xv;                      // == xtf[s], same rounding
    if(s != i) ag -= di*dinv[s]*xv;       // norm_w * x_tan[src]
  }
  size_t b = (size_t)i*64;
  sumn[b+lane] = sn;
  double v = fabs(xtd[b+lane] + ag);      // info = x_tan + agg
  double sc = wsumd(v);
  if(lane==0) keys[i] = (unsigned long long)__double_as_longlong(sc);
}

// ---- K9a: per-level radix histogram (grid-wide, shared agg) ----------------
__global__ void k_hist(const unsigned long long* __restrict__ keys, int N,
                       const unsigned long long* __restrict__ prefp, int lev,
                       int* __restrict__ hist){
  __shared__ int h[256];
  h[threadIdx.x] = 0;
  __syncthreads();
  int shift = 56 - 8*lev;
  unsigned long long pref = *prefp;
  for(int i = blockIdx.x*blockDim.x + threadIdx.x; i<N; i += gridDim.x*blockDim.x){
    unsigned long long kk = keys[i];
    if(lev==0 || (kk >> (shift+8)) == (pref >> (shift+8)))
      atomicAdd(&h[(int)((kk>>shift)&255)], 1);
  }
  __syncthreads();
  if(h[threadIdx.x]) atomicAdd(&hist[threadIdx.x], h[threadIdx.x]);
}

// ---- K9b: pick digit, update pref/rem, re-zero hist ------------------------
__global__ void k_pick(int* __restrict__ hist, unsigned long long* __restrict__ pref,
                       int* __restrict__ rem, int lev){
  __shared__ int h[256];
  h[threadIdx.x] = hist[threadIdx.x];
  __syncthreads();
  hist[threadIdx.x] = 0;                        // reset for next level
  if(threadIdx.x == 0){
    int shift = 56 - 8*lev;
    int r = *rem, cum = 0, chosen = 0;
    for(int d=255; d>=0; --d){
      cum += h[d];
      if(cum >= r){ chosen = d; r -= (cum - h[d]); break; }
    }
    *rem = r;
    *pref |= ((unsigned long long)chosen) << shift;
  }
}

// ---- K10: gather pass C + gate: sum_sel -> gate = sigmoid(...) -------------
__global__ void k_gatherC(const int* __restrict__ csr, const int* __restrict__ rowptr,
                          const float* __restrict__ xtf,
                          const unsigned long long* __restrict__ keys,
                          const unsigned long long* __restrict__ keyT,
                          const float* __restrict__ sumn,
                          const float* __restrict__ lww, const float* __restrict__ lwb,
                          float* __restrict__ gate, int N){
  unsigned long long T = *keyT;
  int lane = threadIdx.x & 63;
  int i = (blockIdx.x*blockDim.x + threadIdx.x)>>6;
  if(i>=N) return;
  int beg = rowptr[i], end = rowptr[i+1];
  float ss = 0.f;
  for(int e=beg; e<end; ++e){
    int s = csr[e];
    if(keys[s] > T) ss += xtf[(size_t)s*64+lane];
  }
  size_t b = (size_t)i*64;
  float z = ss*lww[lane] + sumn[b+lane]*lww[64+lane];
  z = wsumf(z);
  if(lane==0) gate[i] = 1.f/(1.f+expf(-(z+lwb[0])));
}

// ---- K11: gather pass D + final: ax -> out = proj(exp(relu(proj(exp(..)))))-
__global__ void k_gatherD(const int* __restrict__ csr, const int* __restrict__ rowptr,
                          const float* __restrict__ xtf,
                          const unsigned long long* __restrict__ keys,
                          const unsigned long long* __restrict__ keyT,
                          const float* __restrict__ gate,
                          float* __restrict__ out, int N){
  unsigned long long T = *keyT;
  int lane = threadIdx.x & 63;
  int i = (blockIdx.x*blockDim.x + threadIdx.x)>>6;
  if(i>=N) return;
  int beg = rowptr[i], end = rowptr[i+1];
  float ax = 0.f;
  for(int e=beg; e<end; ++e){
    int s = csr[e];
    if(keys[s] > T) ax += gate[s]*xtf[(size_t)s*64+lane];
  }
  size_t b = (size_t)i*64;
  float a = fmaxf(ax, 0.f);                  // relu on aggregate
  float v = xtf[b+lane] + a;
  float n = fmaxf(sqrtf(wsumf(v*v)), 1e-15f);
  float e1 = tanhf(n)*v/n;                   // expmap0
  float en = fmaxf(sqrtf(wsumf(e1*e1)), 1e-15f);
  if(en > MAXN_F) e1 *= MAXN_F/en;           // proj
  e1 = fmaxf(e1, 0.f);                       // relu (HypAct)
  float n2 = fmaxf(sqrtf(wsumf(e1*e1)), 1e-15f);
  float e2 = tanhf(n2)*e1/n2;                // expmap0
  float e2n = fmaxf(sqrtf(wsumf(e2*e2)), 1e-15f);
  if(e2n > MAXN_F) e2 *= MAXN_F/e2n;         // proj
  out[b+lane] = e2;
}

// ---------------------------------------------------------------------------
extern "C" void kernel_launch(void* const* d_in, const int* in_sizes, int n_in,
                              void* d_out, int out_size, void* d_ws, size_t ws_size,
                              hipStream_t stream){
  const float* x    = (const float*)d_in[0];
  const int*   ei   = (const int*)d_in[1];
  const float* W    = (const float*)d_in[2];
  const float* bias = (const float*)d_in[3];
  const float* lww  = (const float*)d_in[4];
  const float* lwb  = (const float*)d_in[5];
  int N = in_sizes[0]/64;
  int E = in_sizes[1]/2;
  int kth = (int)((double)N*0.75);
  int nb = (N+255)/256;                        // scan blocks

  char* ws = (char*)d_ws;
  size_t cur = 0;
  auto alloc = [&](size_t bytes){ size_t o = cur; cur = (cur + bytes + 255) & ~(size_t)255; return o; };
  size_t o_hb   = alloc(64*sizeof(double));
  size_t o_hb2  = alloc(8);
  size_t o_keyT = alloc(8);
  size_t o_rem  = alloc(4);
  size_t o_hist = alloc(256*4);
  size_t o_zero = cur;                         // ---- zeroed region start ----
  size_t o_din  = alloc((size_t)N*4);          // in-degree (CSR)
  size_t o_dout = alloc((size_t)N*4);          // out-degree (s!=d)
  size_t zlen   = cur - o_zero;                // ---- zeroed region end ------
  size_t o_excl = alloc((size_t)N*4);
  size_t o_bsum = alloc((size_t)(nb+1)*4);
  size_t o_rowp = alloc((size_t)(N+1)*4);
  size_t o_curs = alloc((size_t)N*4);
  size_t o_csr  = alloc((size_t)E*4);
  size_t o_dinv = alloc((size_t)N*8);
  size_t o_keys = alloc((size_t)N*8);
  size_t o_sumn = alloc((size_t)N*64*4);
  size_t o_xtf  = alloc((size_t)N*64*4);
  size_t o_xtd  = alloc((size_t)N*64*8);
  size_t o_mx   = alloc((size_t)N*64*8);
  size_t o_r1   = alloc((size_t)N*8);
  size_t o_r2   = alloc((size_t)N*8);
  size_t o_r3   = alloc((size_t)N*8);
  size_t o_al   = alloc((size_t)N*8);
  size_t o_be   = alloc((size_t)N*8);
  size_t o_gate = alloc((size_t)N*4);
  if(ws_size < cur) return;                    // loud, clean failure if ws too small

  double*             hb     = (double*)(ws+o_hb);
  double*             hb2    = (double*)(ws+o_hb2);
  unsigned long long* keyT   = (unsigned long long*)(ws+o_keyT);
  int*                rem    = (int*)(ws+o_rem);
  int*                hist   = (int*)(ws+o_hist);
  int*                degin  = (int*)(ws+o_din);
  int*                degout = (int*)(ws+o_dout);
  int*                excl   = (int*)(ws+o_excl);
  int*                bsum   = (int*)(ws+o_bsum);
  int*                rowptr = (int*)(ws+o_rowp);
  int*                cursor = (int*)(ws+o_curs);
  int*                csr    = (int*)(ws+o_csr);
  double*             dinv   = (double*)(ws+o_dinv);
  unsigned long long* keys   = (unsigned long long*)(ws+o_keys);
  float*              sumn   = (float*)(ws+o_sumn);
  float*              xtf    = (float*)(ws+o_xtf);
  double*             xtd    = (double*)(ws+o_xtd);
  double*             mx     = (double*)(ws+o_mx);
  double*             r1     = (double*)(ws+o_r1);
  double*             r2     = (double*)(ws+o_r2);
  double*             r3     = (double*)(ws+o_r3);
  double*             alpha  = (double*)(ws+o_al);
  double*             beta   = (double*)(ws+o_be);
  float*              gate   = (float*)(ws+o_gate);

  hipMemsetAsync(ws+o_zero, 0, zlen, stream);

  int nodeBlocks = (N+3)/4;                    // 1 wave per node, 4 waves/block
  k_init   <<<1, 256, 0, stream>>>(bias, hb, hb2, keyT, rem, kth, hist);
  k_gemm   <<<(N+NPB-1)/NPB, 256, 0, stream>>>(x, W, hb, mx, r1, r2, r3, N);
  k_chain  <<<(N+255)/256, 256, 0, stream>>>(r1, r2, r3, hb2, alpha, beta, N);
  k_apply  <<<(N*64+255)/256, 256, 0, stream>>>(mx, alpha, beta, hb, xtd, xtf, N);
  k_count  <<<(E+255)/256, 256, 0, stream>>>(ei, degin, degout, E);
  k_dinv   <<<(N+255)/256, 256, 0, stream>>>(degout, dinv, N);
  k_scanA  <<<nb, 256, 0, stream>>>(degin, excl, bsum, N);
  k_scanB  <<<1, 64, 0, stream>>>(bsum, nb);
  k_scanC  <<<nb, 256, 0, stream>>>(excl, bsum, rowptr, cursor, N, E);
  k_scatter<<<(E+255)/256, 256, 0, stream>>>(ei, cursor, csr, E);
  k_gatherA<<<nodeBlocks, 256, 0, stream>>>(csr, rowptr, xtd, dinv, sumn, keys, N);
  for(int lev=0; lev<8; ++lev){
    k_hist<<<256, 256, 0, stream>>>(keys, N, keyT, lev, hist);
    k_pick<<<1, 256, 0, stream>>>(hist, keyT, rem, lev);
  }
  k_gatherC<<<nodeBlocks, 256, 0, stream>>>(csr, rowptr, xtf, keys, keyT, sumn, lww, lwb, gate, N);
  k_gatherD<<<nodeBlocks, 256, 0, stream>>>(csr, rowptr, xtf, keys, keyT, gate, (float*)d_out, N);
}

// Round 5
// 676.038 us; speedup vs baseline: 3.6009x; 1.3514x over previous
//
#include <hip/hip_runtime.h>
#include <math.h>

// ---------------------------------------------------------------------------
// HyperbolicGraphConvolution (HGCN HypLinear + NodeSelect + HypAct), c=1.
// Round 5: gather MLP. Round-4 profile: k_gatherD 176us, 890 GB/s, VALU 28%
// -> latency-bound serial edge loop (1 row in flight/wave). Restructure all
// gathers: 4x16-lane groups = 4 edges in flight/wave, csr prefetch, float4/
// double2 row slices, cross-group shfl combine. Score path stays f64.
// ---------------------------------------------------------------------------

#define MAXN_D 0.996      // (1 - 4e-3)/sqrt(c), c=1
#define MAXN_F 0.996f
#define NPB 16            // nodes per block in k_gemm

__device__ __forceinline__ double wsumd(double v){
#pragma unroll
  for(int o=32;o;o>>=1) v += __shfl_xor(v,o,64);
  return v;
}
// sum within each 16-lane group (lanes sharing lane>>4)
__device__ __forceinline__ double qsumd(double v){
#pragma unroll
  for(int o=1;o<16;o<<=1) v += __shfl_xor(v,o,64);
  return v;
}
__device__ __forceinline__ float qsumf(float v){
#pragma unroll
  for(int o=1;o<16;o<<=1) v += __shfl_xor(v,o,64);
  return v;
}
// sum across the 4 groups (same t = lane&15)
__device__ __forceinline__ double gsumd(double v){
  v += __shfl_xor(v,16,64); v += __shfl_xor(v,32,64); return v;
}
__device__ __forceinline__ float gsumf(float v){
  v += __shfl_xor(v,16,64); v += __shfl_xor(v,32,64); return v;
}

// ---- K0: hyp_bias (double) + |hb|^2 + init select state --------------------
__global__ void k_init(const float* __restrict__ bias, double* __restrict__ hb,
                       double* __restrict__ hb2, unsigned long long* __restrict__ pref,
                       int* __restrict__ rem, int kth, int* __restrict__ hist){
  if(threadIdx.x < 64){
    int lane = threadIdx.x;
    double b = (double)bias[lane];
    double n = fmax(sqrt(wsumd(b*b)), 1e-15);
    double e = tanh(n)*b/n;                       // expmap0, sc=1
    double en = fmax(sqrt(wsumd(e*e)), 1e-15);
    if(en > MAXN_D) e *= MAXN_D/en;               // proj
    hb[lane] = e;
    double s2 = wsumd(e*e);
    if(lane==0) *hb2 = s2;
  }
  hist[threadIdx.x] = 0;
  if(threadIdx.x == 0){ *pref = 0ull; *rem = kth; }
}

// ---- K1: mx = x @ W^T (f64, LDS-tiled) + per-node reductions ---------------
__global__ __launch_bounds__(256) void k_gemm(
    const float* __restrict__ x, const float* __restrict__ W,
    const double* __restrict__ hb, double* __restrict__ mx,
    double* __restrict__ r1, double* __restrict__ r2, double* __restrict__ r3,
    int N){
  __shared__ double wlds[4096];     // double2 [k2][j]: flat (k>>1)*128 + j*2 + (k&1)
  __shared__ double xlds[NPB*64];   // [n][k] f64
  int tid = threadIdx.x;
  for(int idx=tid; idx<4096; idx+=256){
    int j = idx>>6, k = idx&63;
    wlds[(k>>1)*128 + j*2 + (k&1)] = (double)W[idx];
  }
  int i0 = blockIdx.x*NPB;
  for(int idx=tid; idx<NPB*64; idx+=256){
    int node = i0 + (idx>>6);
    xlds[idx] = (node<N) ? (double)x[(size_t)node*64 + (idx&63)] : 0.0;
  }
  __syncthreads();
  int lane = tid & 63;
  int nb = (tid>>6)*4;              // this wave's first node-in-block
  double hbl = hb[lane];
  double acc0=0.0, acc1=0.0, acc2=0.0, acc3=0.0;
  const double2* w2 = (const double2*)wlds;
  const double2* x2 = (const double2*)xlds;
#pragma unroll 4
  for(int k2=0; k2<32; ++k2){
    double2 wt = w2[k2*64 + lane];          // contiguous b128 across lanes
    double2 a  = x2[(nb+0)*32 + k2];        // wave-uniform broadcasts
    double2 b  = x2[(nb+1)*32 + k2];
    double2 c  = x2[(nb+2)*32 + k2];
    double2 d  = x2[(nb+3)*32 + k2];
    acc0 = fma(wt.x, a.x, acc0); acc0 = fma(wt.y, a.y, acc0);
    acc1 = fma(wt.x, b.x, acc1); acc1 = fma(wt.y, b.y, acc1);
    acc2 = fma(wt.x, c.x, acc2); acc2 = fma(wt.y, c.y, acc2);
    acc3 = fma(wt.x, d.x, acc3); acc3 = fma(wt.y, d.y, acc3);
  }
#define DO_NODE(n, accn) { int node = i0 + nb + (n); if(node<N){            \
    double xd = xlds[(nb+(n))*64 + lane];                                   \
    mx[(size_t)node*64 + lane] = accn;                                      \
    double s1 = wsumd(xd*xd);                                               \
    double s2 = wsumd(accn*accn);                                           \
    double s3 = wsumd(accn*hbl);                                            \
    if(lane==0){ r1[node]=s1; r2[node]=s2; r3[node]=s3; } } }
  DO_NODE(0,acc0) DO_NODE(1,acc1) DO_NODE(2,acc2) DO_NODE(3,acc3)
#undef DO_NODE
}

// ---- K2: per-node scalar chain (one LANE per node) -> alpha, beta ----------
__global__ void k_chain(const double* __restrict__ r1, const double* __restrict__ r2,
                        const double* __restrict__ r3, const double* __restrict__ hb2p,
                        double* __restrict__ alpha, double* __restrict__ beta, int N){
  int i = blockIdx.x*blockDim.x + threadIdx.x;
  if(i>=N) return;
  double x2s = r1[i], m2 = r2[i], mh = r3[i];
  double y2 = *hb2p;
  double xn  = fmax(sqrt(x2s), 1e-15);
  double mxn = fmax(sqrt(m2), 1e-15);
  double xc  = fmin(fmax(xn, -1.0+1e-7), 1.0-1e-7);
  double at  = 0.5*(log1p(xc)-log1p(-xc));        // artanh(|x|)
  double f1  = tanh(mxn/xn*at)/mxn;               // h = f1*mx, f1 >= 0
  if(m2 == 0.0) f1 = 0.0;                         // zero-mask (all mx==0)
  double h2 = f1*f1*m2;
  double hn = fmax(sqrt(h2), 1e-15);
  if(hn > MAXN_D){ double s = MAXN_D/hn; f1 *= s; h2 = f1*f1*m2; }   // proj(h)
  // mobius_add(h, hb): p = a*h + b*hb
  double xy = f1*mh;                              // <h, hb>
  double den = fmax(1.0 + 2.0*xy + h2*y2, 1e-15);
  double a = (1.0 + 2.0*xy + y2)/den;
  double b = (1.0 - h2)/den;
  double p2 = a*a*h2 + 2.0*a*b*xy + b*b*y2;       // |p|^2
  double pn = fmax(sqrt(p2), 1e-15);
  if(pn > MAXN_D){ double s = MAXN_D/pn; a*=s; b*=s; pn = fmax(pn*s, 1e-15); } // proj(p)
  double nc  = fmin(fmax(pn, -1.0+1e-7), 1.0-1e-7);
  double at2 = 0.5*(log1p(nc)-log1p(-nc));        // artanh(|p|)
  double sc  = at2/pn;                            // logmap0 scale
  alpha[i] = sc*a*f1;
  beta[i]  = sc*b;
}

// ---- K3: x_tan = alpha*mx + beta*hb (double2 streaming) --------------------
__global__ void k_apply(const double* __restrict__ mx, const double* __restrict__ alpha,
                        const double* __restrict__ beta, const double* __restrict__ hb,
                        double* __restrict__ xtd, float* __restrict__ xtf, int N){
  size_t idx = ((size_t)blockIdx.x*blockDim.x + threadIdx.x)*2;
  if(idx >= (size_t)N*64) return;
  int i = (int)(idx>>6);
  double al = alpha[i], be = beta[i];
  double2 m  = *(const double2*)(mx+idx);
  double2 hv = *(const double2*)(hb+(idx&63));
  double2 v; v.x = al*m.x + be*hv.x; v.y = al*m.y + be*hv.y;
  *(double2*)(xtd+idx) = v;
  float2 f; f.x = (float)v.x; f.y = (float)v.y;
  *(float2*)(xtf+idx) = f;
}

// ---- K4: degrees: in-degree by dst (CSR) + out-degree (s!=d) by src --------
__global__ void k_count(const int* __restrict__ ei, int* __restrict__ degin,
                        int* __restrict__ degout, int E){
  int e = blockIdx.x*blockDim.x + threadIdx.x;
  if(e < E){
    int s = ei[e], d = ei[(size_t)E+e];
    atomicAdd(&degin[d], 1);
    if(s != d) atomicAdd(&degout[s], 1);
  }
}

// ---- K5: dinv = degout>0 ? degout^-0.5 : 0 (double) ------------------------
__global__ void k_dinv(const int* __restrict__ degout, double* __restrict__ dinv, int N){
  int i = blockIdx.x*blockDim.x + threadIdx.x;
  if(i<N){ int d = degout[i]; dinv[i] = (d>0) ? 1.0/sqrt((double)d) : 0.0; }
}

// ---- K6a/b/c: exclusive scan of degin -> rowptr (+ cursor copy) ------------
__global__ void k_scanA(const int* __restrict__ degin, int* __restrict__ excl,
                        int* __restrict__ bsum, int N){
  __shared__ int sh[256];
  int i = blockIdx.x*256 + (int)threadIdx.x;
  int v = (i<N) ? degin[i] : 0;
  sh[threadIdx.x] = v;
  __syncthreads();
  for(int off=1; off<256; off<<=1){
    int t = (threadIdx.x >= (unsigned)off) ? sh[threadIdx.x-off] : 0;
    __syncthreads();
    sh[threadIdx.x] += t;
    __syncthreads();
  }
  if(i<N) excl[i] = sh[threadIdx.x] - v;
  if(threadIdx.x == 255) bsum[blockIdx.x] = sh[255];
}
__global__ void k_scanB(int* __restrict__ bsum, int nb){
  if(threadIdx.x==0){
    int run = 0;
    for(int b=0; b<nb; ++b){ int t = bsum[b]; bsum[b] = run; run += t; }
  }
}
__global__ void k_scanC(const int* __restrict__ excl, const int* __restrict__ bsum,
                        int* __restrict__ rowptr, int* __restrict__ cursor, int N, int E){
  int i = blockIdx.x*256 + (int)threadIdx.x;
  if(i<N){
    int r = excl[i] + bsum[blockIdx.x];
    rowptr[i] = r; cursor[i] = r;
  }
  if(i==0) rowptr[N] = E;
}

// ---- K7: scatter edges into CSR (src list grouped by dst) ------------------
__global__ void k_scatter(const int* __restrict__ ei, int* __restrict__ cursor,
                          int* __restrict__ csr, int E){
  int e = blockIdx.x*blockDim.x + threadIdx.x;
  if(e < E){
    int s = ei[e], d = ei[(size_t)E+e];
    int pos = atomicAdd(&cursor[d], 1);
    csr[pos] = s;
  }
}

// ---- K8: gather A: sum_neigh (f32) + info score key (f64) ------------------
// 4x16-lane groups: group g handles edges j==g (mod 4); lane reads 32B slice.
__global__ void k_gatherA(const int* __restrict__ csr, const int* __restrict__ rowptr,
                          const double* __restrict__ xtd, const double* __restrict__ dinv,
                          float* __restrict__ sumn, unsigned long long* __restrict__ keys,
                          int N){
  int lane = threadIdx.x & 63;
  int i = (blockIdx.x*blockDim.x + threadIdx.x)>>6;
  if(i>=N) return;
  int beg = rowptr[i], deg = rowptr[i+1]-beg;
  int g = lane>>4, t = lane&15;
  double di = dinv[i];
  double a0=0.0,a1=0.0,a2=0.0,a3=0.0;
  float  s0=0.f,s1=0.f,s2=0.f,s3=0.f;
  int j = g;
  int s = (j<deg) ? csr[beg+j] : 0;
  while(j < deg){
    int snext = (j+4<deg) ? csr[beg+j+4] : 0;       // prefetch next index
    const double2* row = (const double2*)(xtd + (size_t)s*64 + t*4);
    double2 v0 = row[0], v1 = row[1];
    s0 += (float)v0.x; s1 += (float)v0.y; s2 += (float)v1.x; s3 += (float)v1.y;
    if(s != i){
      double w = di*dinv[s];
      a0 -= w*v0.x; a1 -= w*v0.y; a2 -= w*v1.x; a3 -= w*v1.y;
    }
    s = snext; j += 4;
  }
  a0 = gsumd(a0); a1 = gsumd(a1); a2 = gsumd(a2); a3 = gsumd(a3);
  s0 = gsumf(s0); s1 = gsumf(s1); s2 = gsumf(s2); s3 = gsumf(s3);
  if(g==0){
    float4 sv = make_float4(s0,s1,s2,s3);
    *((float4*)(sumn + (size_t)i*64 + t*4)) = sv;
  }
  const double2* xr = (const double2*)(xtd + (size_t)i*64 + t*4);
  double2 x0 = xr[0], x1 = xr[1];
  double sc = fabs(x0.x+a0) + fabs(x0.y+a1) + fabs(x1.x+a2) + fabs(x1.y+a3);
  sc = qsumd(sc);                                   // sum over t within group
  if(lane==0) keys[i] = (unsigned long long)__double_as_longlong(sc);
}

// ---- K9a: per-level radix histogram (grid-wide, shared agg) ----------------
__global__ void k_hist(const unsigned long long* __restrict__ keys, int N,
                       const unsigned long long* __restrict__ prefp, int lev,
                       int* __restrict__ hist){
  __shared__ int h[256];
  h[threadIdx.x] = 0;
  __syncthreads();
  int shift = 56 - 8*lev;
  unsigned long long pref = *prefp;
  for(int i = blockIdx.x*blockDim.x + threadIdx.x; i<N; i += gridDim.x*blockDim.x){
    unsigned long long kk = keys[i];
    if(lev==0 || (kk >> (shift+8)) == (pref >> (shift+8)))
      atomicAdd(&h[(int)((kk>>shift)&255)], 1);
  }
  __syncthreads();
  if(h[threadIdx.x]) atomicAdd(&hist[threadIdx.x], h[threadIdx.x]);
}

// ---- K9b: pick digit, update pref/rem, re-zero hist ------------------------
__global__ void k_pick(int* __restrict__ hist, unsigned long long* __restrict__ pref,
                       int* __restrict__ rem, int lev){
  __shared__ int h[256];
  h[threadIdx.x] = hist[threadIdx.x];
  __syncthreads();
  hist[threadIdx.x] = 0;                        // reset for next level
  if(threadIdx.x == 0){
    int shift = 56 - 8*lev;
    int r = *rem, cum = 0, chosen = 0;
    for(int d=255; d>=0; --d){
      cum += h[d];
      if(cum >= r){ chosen = d; r -= (cum - h[d]); break; }
    }
    *rem = r;
    *pref |= ((unsigned long long)chosen) << shift;
  }
}

// ---- K10: gather C + gate: sum_sel -> gate = sigmoid(...) ------------------
__global__ void k_gatherC(const int* __restrict__ csr, const int* __restrict__ rowptr,
                          const float* __restrict__ xtf,
                          const unsigned long long* __restrict__ keys,
                          const unsigned long long* __restrict__ keyT,
                          const float* __restrict__ sumn,
                          const float* __restrict__ lww, const float* __restrict__ lwb,
                          float* __restrict__ gate, int N){
  unsigned long long T = *keyT;
  int lane = threadIdx.x & 63;
  int i = (blockIdx.x*blockDim.x + threadIdx.x)>>6;
  if(i>=N) return;
  int beg = rowptr[i], deg = rowptr[i+1]-beg;
  int g = lane>>4, t = lane&15;
  float c0=0.f,c1=0.f,c2=0.f,c3=0.f;
  int j = g;
  int s = (j<deg) ? csr[beg+j] : 0;
  while(j < deg){
    int snext = (j+4<deg) ? csr[beg+j+4] : 0;
    if(keys[s] > T){
      float4 v = *((const float4*)(xtf + (size_t)s*64 + t*4));
      c0 += v.x; c1 += v.y; c2 += v.z; c3 += v.w;
    }
    s = snext; j += 4;
  }
  c0 = gsumf(c0); c1 = gsumf(c1); c2 = gsumf(c2); c3 = gsumf(c3);
  float4 sn = *((const float4*)(sumn + (size_t)i*64 + t*4));
  float4 wA = *((const float4*)(lww + t*4));
  float4 wB = *((const float4*)(lww + 64 + t*4));
  float z = c0*wA.x + c1*wA.y + c2*wA.z + c3*wA.w
          + sn.x*wB.x + sn.y*wB.y + sn.z*wB.z + sn.w*wB.w;
  z = qsumf(z);
  if(lane==0) gate[i] = 1.f/(1.f+expf(-(z+lwb[0])));
}

// ---- K11: gather D + final chain -------------------------------------------
__global__ void k_gatherD(const int* __restrict__ csr, const int* __restrict__ rowptr,
                          const float* __restrict__ xtf,
                          const unsigned long long* __restrict__ keys,
                          const unsigned long long* __restrict__ keyT,
                          const float* __restrict__ gate,
                          float* __restrict__ out, int N){
  unsigned long long T = *keyT;
  int lane = threadIdx.x & 63;
  int i = (blockIdx.x*blockDim.x + threadIdx.x)>>6;
  if(i>=N) return;
  int beg = rowptr[i], deg = rowptr[i+1]-beg;
  int g = lane>>4, t = lane&15;
  float c0=0.f,c1=0.f,c2=0.f,c3=0.f;
  int j = g;
  int s = (j<deg) ? csr[beg+j] : 0;
  while(j < deg){
    int snext = (j+4<deg) ? csr[beg+j+4] : 0;
    if(keys[s] > T){
      float gv = gate[s];
      float4 v = *((const float4*)(xtf + (size_t)s*64 + t*4));
      c0 = fmaf(gv, v.x, c0); c1 = fmaf(gv, v.y, c1);
      c2 = fmaf(gv, v.z, c2); c3 = fmaf(gv, v.w, c3);
    }
    s = snext; j += 4;
  }
  c0 = gsumf(c0); c1 = gsumf(c1); c2 = gsumf(c2); c3 = gsumf(c3);
  float4 xr = *((const float4*)(xtf + (size_t)i*64 + t*4));
  float v0 = xr.x + fmaxf(c0,0.f);
  float v1 = xr.y + fmaxf(c1,0.f);
  float v2 = xr.z + fmaxf(c2,0.f);
  float v3 = xr.w + fmaxf(c3,0.f);
  float n2 = qsumf(v0*v0 + v1*v1 + v2*v2 + v3*v3);     // |v|^2 (full 64-dim)
  float n = fmaxf(sqrtf(n2), 1e-15f);
  float f = tanhf(n)/n;                                // expmap0 scale
  float e0=f*v0, e1=f*v1, e2=f*v2, e3=f*v3;
  float en = fmaxf(tanhf(n), 1e-15f);                  // |e| = tanh(n)
  if(en > MAXN_F){ float sf = MAXN_F/en; e0*=sf; e1*=sf; e2*=sf; e3*=sf; }
  e0 = fmaxf(e0,0.f); e1 = fmaxf(e1,0.f); e2 = fmaxf(e2,0.f); e3 = fmaxf(e3,0.f);
  float m2 = qsumf(e0*e0 + e1*e1 + e2*e2 + e3*e3);     // |relu(e)|^2
  float nb = fmaxf(sqrtf(m2), 1e-15f);
  float f2 = tanhf(nb)/nb;
  float o0=f2*e0, o1=f2*e1, o2=f2*e2, o3=f2*e3;
  float on = fmaxf(tanhf(nb), 1e-15f);
  if(on > MAXN_F){ float sf = MAXN_F/on; o0*=sf; o1*=sf; o2*=sf; o3*=sf; }
  if(g==0){
    float4 ov = make_float4(o0,o1,o2,o3);
    *((float4*)(out + (size_t)i*64 + t*4)) = ov;
  }
}

// ---------------------------------------------------------------------------
extern "C" void kernel_launch(void* const* d_in, const int* in_sizes, int n_in,
                              void* d_out, int out_size, void* d_ws, size_t ws_size,
                              hipStream_t stream){
  const float* x    = (const float*)d_in[0];
  const int*   ei   = (const int*)d_in[1];
  const float* W    = (const float*)d_in[2];
  const float* bias = (const float*)d_in[3];
  const float* lww  = (const float*)d_in[4];
  const float* lwb  = (const float*)d_in[5];
  int N = in_sizes[0]/64;
  int E = in_sizes[1]/2;
  int kth = (int)((double)N*0.75);
  int nb = (N+255)/256;                        // scan blocks

  char* ws = (char*)d_ws;
  size_t cur = 0;
  auto alloc = [&](size_t bytes){ size_t o = cur; cur = (cur + bytes + 255) & ~(size_t)255; return o; };
  size_t o_hb   = alloc(64*sizeof(double));
  size_t o_hb2  = alloc(8);
  size_t o_keyT = alloc(8);
  size_t o_rem  = alloc(4);
  size_t o_hist = alloc(256*4);
  size_t o_zero = cur;                         // ---- zeroed region start ----
  size_t o_din  = alloc((size_t)N*4);          // in-degree (CSR)
  size_t o_dout = alloc((size_t)N*4);          // out-degree (s!=d)
  size_t zlen   = cur - o_zero;                // ---- zeroed region end ------
  size_t o_excl = alloc((size_t)N*4);
  size_t o_bsum = alloc((size_t)(nb+1)*4);
  size_t o_rowp = alloc((size_t)(N+1)*4);
  size_t o_curs = alloc((size_t)N*4);
  size_t o_csr  = alloc((size_t)E*4);
  size_t o_dinv = alloc((size_t)N*8);
  size_t o_keys = alloc((size_t)N*8);
  size_t o_sumn = alloc((size_t)N*64*4);
  size_t o_xtf  = alloc((size_t)N*64*4);
  size_t o_xtd  = alloc((size_t)N*64*8);
  size_t o_mx   = alloc((size_t)N*64*8);
  size_t o_r1   = alloc((size_t)N*8);
  size_t o_r2   = alloc((size_t)N*8);
  size_t o_r3   = alloc((size_t)N*8);
  size_t o_al   = alloc((size_t)N*8);
  size_t o_be   = alloc((size_t)N*8);
  size_t o_gate = alloc((size_t)N*4);
  if(ws_size < cur) return;                    // loud, clean failure if ws too small

  double*             hb     = (double*)(ws+o_hb);
  double*             hb2    = (double*)(ws+o_hb2);
  unsigned long long* keyT   = (unsigned long long*)(ws+o_keyT);
  int*                rem    = (int*)(ws+o_rem);
  int*                hist   = (int*)(ws+o_hist);
  int*                degin  = (int*)(ws+o_din);
  int*                degout = (int*)(ws+o_dout);
  int*                excl   = (int*)(ws+o_excl);
  int*                bsum   = (int*)(ws+o_bsum);
  int*                rowptr = (int*)(ws+o_rowp);
  int*                cursor = (int*)(ws+o_curs);
  int*                csr    = (int*)(ws+o_csr);
  double*             dinv   = (double*)(ws+o_dinv);
  unsigned long long* keys   = (unsigned long long*)(ws+o_keys);
  float*              sumn   = (float*)(ws+o_sumn);
  float*              xtf    = (float*)(ws+o_xtf);
  double*             xtd    = (double*)(ws+o_xtd);
  double*             mx     = (double*)(ws+o_mx);
  double*             r1     = (double*)(ws+o_r1);
  double*             r2     = (double*)(ws+o_r2);
  double*             r3     = (double*)(ws+o_r3);
  double*             alpha  = (double*)(ws+o_al);
  double*             beta   = (double*)(ws+o_be);
  float*              gate   = (float*)(ws+o_gate);

  hipMemsetAsync(ws+o_zero, 0, zlen, stream);

  int nodeBlocks = (N+3)/4;                    // 1 wave per node, 4 waves/block
  k_init   <<<1, 256, 0, stream>>>(bias, hb, hb2, keyT, rem, kth, hist);
  k_gemm   <<<(N+NPB-1)/NPB, 256, 0, stream>>>(x, W, hb, mx, r1, r2, r3, N);
  k_chain  <<<(N+255)/256, 256, 0, stream>>>(r1, r2, r3, hb2, alpha, beta, N);
  k_apply  <<<(N*32+255)/256, 256, 0, stream>>>(mx, alpha, beta, hb, xtd, xtf, N);
  k_count  <<<(E+255)/256, 256, 0, stream>>>(ei, degin, degout, E);
  k_dinv   <<<(N+255)/256, 256, 0, stream>>>(degout, dinv, N);
  k_scanA  <<<nb, 256, 0, stream>>>(degin, excl, bsum, N);
  k_scanB  <<<1, 64, 0, stream>>>(bsum, nb);
  k_scanC  <<<nb, 256, 0, stream>>>(excl, bsum, rowptr, cursor, N, E);
  k_scatter<<<(E+255)/256, 256, 0, stream>>>(ei, cursor, csr, E);
  k_gatherA<<<nodeBlocks, 256, 0, stream>>>(csr, rowptr, xtd, dinv, sumn, keys, N);
  for(int lev=0; lev<8; ++lev){
    k_hist<<<256, 256, 0, stream>>>(keys, N, keyT, lev, hist);
    k_pick<<<1, 256, 0, stream>>>(hist, keyT, rem, lev);
  }
  k_gatherC<<<nodeBlocks, 256, 0, stream>>>(csr, rowptr, xtf, keys, keyT, sumn, lww, lwb, gate, N);
  k_gatherD<<<nodeBlocks, 256, 0, stream>>>(csr, rowptr, xtf, keys, keyT, gate, (float*)d_out, N);
}